// Round 6
// baseline (103.685 us; speedup 1.0000x reference)
//
#include <hip/hip_runtime.h>
#include <math.h>

// TV-1D prox via FGP on the dual, 30 fixed iterations.
// R6: TWO rows per wave — each 32-lane half-wave owns a full 256-elem row,
// 8 elems/lane in registers. Halves the LDS-pipe shuffle count per row
// (2 bperm/wave/iter amortized over 2 rows) and triples the independent
// VALU work schedulable under each bperm's lgkm wait.
// Boundary wiring is mask-free via the pinned-dummy-slot invariant:
// each half-row's dual slot 255 (hl==31, j==7) is pinned to +-0 every
// iteration by its med3 bounds (lam7=0); all bperm wraps and cross-row
// halo leaks land on pinned slots. Loop body: 48 VALU + 2 LDS ops per
// wave per iter = the 6-inst/elem structural floor, 1 shuffle/row/iter.

constexpr int N_ITERS = 30;

struct Coefs { float c[N_ITERS]; };

// lane n <- lane n+1, lane 63 <- 0 (one-time x halo; lane31 cross-row
// garbage only ever feeds the pinned slot-7 path)
__device__ __forceinline__ float dpp_dn1_z(float v) {
    return __int_as_float(__builtin_amdgcn_update_dpp(
        0, __float_as_int(v), 0x130 /*wave_shl:1*/, 0xf, 0xf, true));
}
// LDS-pipe lane gather: lane i <- lane (idx>>2)&63
__device__ __forceinline__ float bperm(int idx, float v) {
    return __int_as_float(__builtin_amdgcn_ds_bpermute(idx, __float_as_int(v)));
}

__global__ __launch_bounds__(256, 8)
void tv1d_prox_kernel(const float* __restrict__ x,
                      const float* __restrict__ lmbd_param,
                      float* __restrict__ out,
                      Coefs co)
{
    const int lane = threadIdx.x & 63;
    const int hl   = lane & 31;                     // position within the half-wave row
    const int row  = (blockIdx.x << 3) | (threadIdx.x >> 5);   // 8 rows / 256-thr block
    const int chan = (row >> 7) & 31;               // dims (8,32,128,256)

    const float p    = lmbd_param[chan];
    const float lam  = log1pf(expf(p));             // softplus (per-lane; rows may straddle chans)
    const float nlam = -lam;

    // shift indices: bperm uses addr bits[7:2] (wraps mod 64)
    const int idx_up = (lane << 2) - 4;  // lane-1; lane0->63.y7 (pinned 0), lane32->31.y7 (pinned 0)
    const int idx_dn = (lane << 2) + 4;  // lane+1; lane31->32.y0 / lane63->0.y0 (cross-row -> pinned v7)

    // slot-7 clamp bounds: 0 at hl==31 => med3 pins each row's dummy dual slot to +-0
    const float lam7  = (hl == 31) ? 0.f : lam;
    const float nlam7 = -lam7;

    // row-contiguous load: half-wave covers 1024B via two dwordx4 (stride 32B/lane)
    const float4* xv4 = reinterpret_cast<const float4*>(x);
    const int base = (row << 6) | (hl << 1);
    const float4 xa = xv4[base];
    const float4 xb = xv4[base + 1];
    float xr[8] = {xa.x, xa.y, xa.z, xa.w, xb.x, xb.y, xb.z, xb.w};
    const float x8 = dpp_dn1_z(xr[0]);              // halo x[8hl+8]

    // loop-invariant: dx[j] = 0.25*(x[j+1]-x[j]);  dx7 garbage at hl==31 -> pinned path only
    float dx[8];
#pragma unroll
    for (int j = 0; j < 7; ++j) dx[j] = 0.25f * (xr[j + 1] - xr[j]);
    dx[7] = 0.25f * (x8 - xr[7]);

    // Iteration 0 peeled: y=u=0 -> v = dx; c0 = 0 -> y = u = clip(dx).
    float u[8], y[8];
#pragma unroll
    for (int j = 0; j < 7; ++j) u[j] = __builtin_amdgcn_fmed3f(dx[j], nlam, lam);
    u[7] = __builtin_amdgcn_fmed3f(dx[7], nlam7, lam7);     // hl31 -> +-0
#pragma unroll
    for (int j = 0; j < 8; ++j) y[j] = u[j];

#pragma unroll
    for (int it = 1; it < N_ITERS; ++it) {
        const float ypl = bperm(idx_up, y[7]);      // y[8hl-1]; boundary lanes read pinned +-0
        const float ynf = bperm(idx_dn, y[0]);      // y[8hl+8]; cross-row -> pinned v7 only

        // v[j] = 0.5*y[j] + dx[j] + 0.25*(y[j-1] + y[j+1])
        float s[8];
        s[0] = ypl + y[1];
#pragma unroll
        for (int j = 1; j < 7; ++j) s[j] = y[j - 1] + y[j + 1];
        s[7] = y[6] + ynf;

        float v[8];
#pragma unroll
        for (int j = 0; j < 8; ++j)
            v[j] = fmaf(0.25f, s[j], fmaf(0.5f, y[j], dx[j]));
#pragma unroll
        for (int j = 0; j < 7; ++j) v[j] = __builtin_amdgcn_fmed3f(v[j], nlam, lam);
        v[7] = __builtin_amdgcn_fmed3f(v[7], nlam7, lam7);  // hl31 pinned to +-0

        if (it < N_ITERS - 1) {                     // folds at compile time (unrolled)
            const float c = co.c[it];               // y_next = v + c*(v - u_prev)
#pragma unroll
            for (int j = 0; j < 8; ++j) y[j] = fmaf(c, v[j] - u[j], v[j]);
        }
#pragma unroll
        for (int j = 0; j < 8; ++j) u[j] = v[j];
    }

    // out = x - Dt(u_final);  out[i] = x[i] - u[i-1] + u[i]
    const float upl = bperm(idx_up, u[7]);          // boundary lanes read pinned +-0

    float o[8];
    o[0] = xr[0] - upl + u[0];
#pragma unroll
    for (int j = 1; j < 8; ++j) o[j] = xr[j] - u[j - 1] + u[j];   // hl31: u7==+-0 exact

    float4* ov4 = reinterpret_cast<float4*>(out);
    ov4[base]     = make_float4(o[0], o[1], o[2], o[3]);
    ov4[base + 1] = make_float4(o[4], o[5], o[6], o[7]);
}

extern "C" void kernel_launch(void* const* d_in, const int* in_sizes, int n_in,
                              void* d_out, int out_size, void* d_ws, size_t ws_size,
                              hipStream_t stream)
{
    const float* x    = (const float*)d_in[0];
    const float* lmbd = (const float*)d_in[1];
    float* out        = (float*)d_out;

    // t-sequence is data-independent: bake (t_k - 1)/t_{k+1} into kernargs.
    Coefs co;
    float t = 1.0f;
    for (int k = 0; k < N_ITERS; ++k) {
        const float tn = 0.5f * (1.0f + sqrtf(1.0f + 4.0f * t * t));
        co.c[k] = (t - 1.0f) / tn;
        t = tn;
    }

    const int rows   = out_size / 256;   // 32768
    const int blocks = rows / 8;         // 8 rows (4 waves x 2 half-rows) per block
    tv1d_prox_kernel<<<blocks, 256, 0, stream>>>(x, lmbd, out, co);
}